// Round 11
// baseline (62.078 us; speedup 1.0000x reference)
//
#include <hip/hip_runtime.h>
#include <math.h>

#define D     1024
#define D4    256     // D/4
#define BI    48
#define BC    48
#define RR    36
#define TT    40
#define EPSF  1e-5f
#define PRG   128     // cap-stat row groups
#define CROWS 15      // rows per group (128*15 = 1920)
#define L2E   1.4426950408889634f

typedef float f2 __attribute__((ext_vector_type(2)));

static __device__ __forceinline__ f2 f2max(f2 a, f2 b) {
    f2 r; r.x = fmaxf(a.x, b.x); r.y = fmaxf(a.y, b.y); return r;
}

// ---- K1: cap BN partial sums (blocks 0..127) + img_q/img_n (blocks 128..175)
__global__ __launch_bounds__(256) void k_stats(const float* __restrict__ cap,
                                               const float* __restrict__ img,
                                               float* __restrict__ ps,
                                               float* __restrict__ pss,
                                               float* __restrict__ img_q,
                                               float* __restrict__ img_n) {
    __shared__ float sw[4];
    int bx = blockIdx.x, tid = threadIdx.x;
    if (bx < PRG) {
        const float4* cap4 = (const float4*)cap;
        float4 s = {0,0,0,0}, ss = {0,0,0,0};
        int r0 = bx * CROWS;
#pragma unroll
        for (int r = 0; r < CROWS; ++r) {
            float4 v = cap4[(size_t)(r0 + r) * D4 + tid];
            s.x += v.x; s.y += v.y; s.z += v.z; s.w += v.w;
            ss.x += v.x*v.x; ss.y += v.y*v.y; ss.z += v.z*v.z; ss.w += v.w*v.w;
        }
        ((float4*)ps)[(size_t)bx * D4 + tid]  = s;
        ((float4*)pss)[(size_t)bx * D4 + tid] = ss;
    } else {
        int i = bx - PRG;
        const float4* img4 = (const float4*)img;
        float4 s = {0,0,0,0};
#pragma unroll
        for (int r = 0; r < RR; ++r) {
            float4 v = img4[((size_t)i * RR + r) * D4 + tid];
            s.x += v.x; s.y += v.y; s.z += v.z; s.w += v.w;
        }
        const float inv = 1.f / 36.f;
        float4 q = {s.x*inv, s.y*inv, s.z*inv, s.w*inv};
        ((float4*)img_q)[(size_t)i * D4 + tid] = q;
        float ssq = q.x*q.x + q.y*q.y + q.z*q.z + q.w*q.w;
#pragma unroll
        for (int off = 32; off; off >>= 1) ssq += __shfl_xor(ssq, off, 64);
        if ((tid & 63) == 0) sw[tid >> 6] = ssq;
        __syncthreads();
        float rinv = rsqrtf(sw[0] + sw[1] + sw[2] + sw[3]);
        float4 n = {q.x*rinv, q.y*rinv, q.z*rinv, q.w*rinv};
        ((float4*)img_n)[(size_t)i * D4 + tid] = n;
    }
}

// ---- K2: FiLM GEMMs — 128-thread blocks, 2 waves x 2 rows (blocks 0..511)
//          + BN finalize (512..519). 2 blocks/CU uniform; q LDS reads
//          amortized over 2 rows -> per-CU LDS-pipe work halved vs 1-row/wave.
__global__ __launch_bounds__(128) void k_film(const float* __restrict__ img_q,
                                              const float* __restrict__ Wg,
                                              const float* __restrict__ bg,
                                              const float* __restrict__ Wb,
                                              const float* __restrict__ bb,
                                              const float* __restrict__ ps,
                                              const float* __restrict__ pss,
                                              float* __restrict__ g1,
                                              float* __restrict__ be,
                                              float* __restrict__ mean,
                                              float* __restrict__ scale) {
    __shared__ float smem[12288];            // 49152 B: lq4 stage / tail scratch
    float4* lq4 = (float4*)smem;
    int tid = threadIdx.x;

    if (blockIdx.x >= 512) {                 // ---- BN finalize: 8 blocks (128 thr)
        int bx2 = blockIdx.x - 512;          // 0..7
        int c32 = tid & 31;
        int col = bx2 * 32 + c32;            // float4 column 0..255
        int rs  = tid >> 5;                  // 0..3 row-subsets
        const float4* ps4  = (const float4*)ps;
        const float4* pss4 = (const float4*)pss;
        float4 s = {0,0,0,0}, q = {0,0,0,0};
#pragma unroll
        for (int gi = 0; gi < PRG / 4; ++gi) {
            int rg = rs * (PRG / 4) + gi;
            float4 a  = ps4[(size_t)rg * D4 + col];
            float4 b2 = pss4[(size_t)rg * D4 + col];
            s.x += a.x;  s.y += a.y;  s.z += a.z;  s.w += a.w;
            q.x += b2.x; q.y += b2.y; q.z += b2.z; q.w += b2.w;
        }
        float4* red = lq4;
        red[rs * 32 + c32]       = s;
        red[128 + rs * 32 + c32] = q;
        __syncthreads();
        if (rs == 0) {
            float4 S = {0,0,0,0}, Q = {0,0,0,0};
#pragma unroll
            for (int r2 = 0; r2 < 4; ++r2) {
                float4 a  = red[r2 * 32 + c32];
                float4 b2 = red[128 + r2 * 32 + c32];
                S.x += a.x;  S.y += a.y;  S.z += a.z;  S.w += a.w;
                Q.x += b2.x; Q.y += b2.y; Q.z += b2.z; Q.w += b2.w;
            }
            const float inv = 1.f / 1920.f;
            float4 M = {S.x*inv, S.y*inv, S.z*inv, S.w*inv};
            float4 SC;
            SC.x = rsqrtf(Q.x*inv - M.x*M.x + EPSF);
            SC.y = rsqrtf(Q.y*inv - M.y*M.y + EPSF);
            SC.z = rsqrtf(Q.z*inv - M.z*M.z + EPSF);
            SC.w = rsqrtf(Q.w*inv - M.w*M.w + EPSF);
            ((float4*)mean)[col]  = M;
            ((float4*)scale)[col] = SC;
        }
        return;
    }

    // ---- FiLM GEMM: wave = 2 adjacent rows (even base; never crosses 1024)
    int wave = tid >> 6, lane = tid & 63;
    int row0 = blockIdx.x * 4 + wave * 2;    // block covers rows 4b..4b+3
    int isbeta = row0 >> 10;
    int d0 = row0 & 1023;                    // even; d1 = d0 + 1
    const float4* W4 = (const float4*)(isbeta ? Wb : Wg);

    // prefetch both rows' W chunks (latency overlaps kc0 staging)
    float4 wv0[4], wv1[4];
#pragma unroll
    for (int kc = 0; kc < 4; ++kc) {
        wv0[kc] = W4[(size_t)d0 * D4 + kc * 64 + lane];
        wv1[kc] = W4[(size_t)(d0 + 1) * D4 + kc * 64 + lane];
    }

    float acc0[BI], acc1[BI];
#pragma unroll
    for (int i = 0; i < BI; ++i) { acc0[i] = 0.f; acc1[i] = 0.f; }

    const float4* q4g = (const float4*)img_q;
#pragma unroll
    for (int kc = 0; kc < 4; ++kc) {
        __syncthreads();
        for (int idx = tid; idx < BI * 64; idx += 128) {
            int i = idx >> 6, kk = idx & 63;
            lq4[idx] = q4g[(size_t)i * D4 + kc * 64 + kk];
        }
        __syncthreads();
#pragma unroll
        for (int i = 0; i < BI; ++i) {
            float4 q = lq4[i * 64 + lane];
            acc0[i] = fmaf(wv0[kc].x, q.x, acc0[i]);
            acc0[i] = fmaf(wv0[kc].y, q.y, acc0[i]);
            acc0[i] = fmaf(wv0[kc].z, q.z, acc0[i]);
            acc0[i] = fmaf(wv0[kc].w, q.w, acc0[i]);
            acc1[i] = fmaf(wv1[kc].x, q.x, acc1[i]);
            acc1[i] = fmaf(wv1[kc].y, q.y, acc1[i]);
            acc1[i] = fmaf(wv1[kc].z, q.z, acc1[i]);
            acc1[i] = fmaf(wv1[kc].w, q.w, acc1[i]);
        }
    }
    // transpose-reduce per row in wave-private LDS (stride 49, conflict-free).
    // DS ops within a wave are ordered -> no barrier between the two rounds.
    __syncthreads();                         // both waves done reading lq4
    float* tr = smem + wave * 3136;          // 64*49 floats, wave-private
    float* outp = isbeta ? be : g1;
#pragma unroll
    for (int r = 0; r < 2; ++r) {
        const float* acc = r ? acc1 : acc0;
#pragma unroll
        for (int i = 0; i < BI; ++i) tr[lane * 49 + i] = acc[i];
        float a0 = 0.f, a1 = 0.f, a2 = 0.f, a3 = 0.f;
#pragma unroll
        for (int l = 0; l < 64; l += 4) {
            a0 += tr[(l + 0) * 49 + lane];
            a1 += tr[(l + 1) * 49 + lane];
            a2 += tr[(l + 2) * 49 + lane];
            a3 += tr[(l + 3) * 49 + lane];
        }
        float sum = (a0 + a1) + (a2 + a3);
        int d = d0 + r;
        if (lane < BI) {
            float badd = isbeta ? bb[d] : (bg[d] + 1.f);   // store 1+gamma
            outp[(size_t)lane * D + d] = sum + badd;
        }
    }
}

// ---- K3: fused BN-normalize + Fovea + l2norm + cosine. (unchanged from R8)
// 768 blocks = (b, 3 images); packed-f32 math; XCD-bijective swizzle.
// log2e fold: y = x*log2e, e=2^y; vm/se carries a log2e factor (positive,
// same for all d of an (i,b) pair) -> cancels in the l2 normalization.
__global__ __launch_bounds__(256) void k_fovea(const float* __restrict__ cap,
                                               const float* __restrict__ mean,
                                               const float* __restrict__ scale,
                                               const float* __restrict__ g1,
                                               const float* __restrict__ be,
                                               const float* __restrict__ img_n,
                                               float* __restrict__ out) {
    int j = blockIdx.x;                      // 768 items
    int wg = (j & 7) * 96 + (j >> 3);        // bijective XCD swizzle (768 % 8 == 0)
    int b = wg >> 4, ig = wg & 15;
    int i0 = ig * 3;
    int tid = threadIdx.x;

    const float4* cap4 = (const float4*)cap;
    float4 m4  = ((const float4*)mean)[tid];
    float4 sc4 = ((const float4*)scale)[tid];
    f2 mm0 = {m4.x, m4.y},  mm1 = {m4.z, m4.w};
    f2 sc0 = {sc4.x, sc4.y}, sc1 = {sc4.z, sc4.w};

    // G2 = g*sc*L2E ; B2 = (bt - g*sc*m)*L2E
    f2 G2[3][2], B2[3][2];
#pragma unroll
    for (int u = 0; u < 3; ++u) {
        float4 t0 = ((const float4*)g1)[(size_t)(i0 + u) * D4 + tid];
        float4 u0 = ((const float4*)be)[(size_t)(i0 + u) * D4 + tid];
        f2 gg0 = {t0.x, t0.y}, gg1 = {t0.z, t0.w};
        f2 bt0 = {u0.x, u0.y}, bt1 = {u0.z, u0.w};
        f2 tt0 = gg0 * sc0, tt1 = gg1 * sc1;
        G2[u][0] = tt0 * L2E;
        G2[u][1] = tt1 * L2E;
        B2[u][0] = (bt0 - tt0 * mm0) * L2E;
        B2[u][1] = (bt1 - tt1 * mm1) * L2E;
    }
    f2 se[3][2], vm[3][2];
#pragma unroll
    for (int u = 0; u < 3; ++u)
#pragma unroll
        for (int c = 0; c < 2; ++c) {
            se[u][c] = (f2){0.f, 0.f};
            vm[u][c] = (f2){-INFINITY, -INFINITY};
        }

#pragma unroll 4
    for (int t = 0; t < TT; ++t) {
        float4 c4 = cap4[((size_t)b * TT + t) * D4 + tid];
        f2 cc0 = {c4.x, c4.y}, cc1 = {c4.z, c4.w};
#pragma unroll
        for (int u = 0; u < 3; ++u) {
            f2 y0 = cc0 * G2[u][0] + B2[u][0];
            f2 y1 = cc1 * G2[u][1] + B2[u][1];
            f2 e0, e1;
            e0.x = __builtin_amdgcn_exp2f(y0.x);
            e0.y = __builtin_amdgcn_exp2f(y0.y);
            e1.x = __builtin_amdgcn_exp2f(y1.x);
            e1.y = __builtin_amdgcn_exp2f(y1.y);
            se[u][0] += e0;
            se[u][1] += e1;
            vm[u][0] = f2max(vm[u][0], y0 * e0);
            vm[u][1] = f2max(vm[u][1], y1 * e1);
        }
    }
    float dd[3], sq[3];
#pragma unroll
    for (int u = 0; u < 3; ++u) {
        float4 nn = ((const float4*)img_n)[(size_t)(i0 + u) * D4 + tid];
        f2 r0, r1;
        r0.x = __builtin_amdgcn_rcpf(se[u][0].x);
        r0.y = __builtin_amdgcn_rcpf(se[u][0].y);
        r1.x = __builtin_amdgcn_rcpf(se[u][1].x);
        r1.y = __builtin_amdgcn_rcpf(se[u][1].y);
        f2 v0 = vm[u][0] * r0, v1 = vm[u][1] * r1;
        sq[u] = v0.x*v0.x + v0.y*v0.y + v1.x*v1.x + v1.y*v1.y;
        dd[u] = v0.x*nn.x + v0.y*nn.y + v1.x*nn.z + v1.y*nn.w;
    }
#pragma unroll
    for (int off = 32; off; off >>= 1) {
#pragma unroll
        for (int u = 0; u < 3; ++u) {
            dd[u] += __shfl_xor(dd[u], off, 64);
            sq[u] += __shfl_xor(sq[u], off, 64);
        }
    }
    __shared__ float rd[3][4], rq[3][4];     // [u][wave]
    int wave = tid >> 6, lane = tid & 63;
    if (lane == 0) {
#pragma unroll
        for (int u = 0; u < 3; ++u) { rd[u][wave] = dd[u]; rq[u][wave] = sq[u]; }
    }
    __syncthreads();
    if (tid < 3) {
        float td = rd[tid][0] + rd[tid][1] + rd[tid][2] + rd[tid][3];
        float ts = rq[tid][0] + rq[tid][1] + rq[tid][2] + rq[tid][3];
        out[(size_t)(i0 + tid) * BC + b] = td / sqrtf(ts);
    }
}

extern "C" void kernel_launch(void* const* d_in, const int* in_sizes, int n_in,
                              void* d_out, int out_size, void* d_ws, size_t ws_size,
                              hipStream_t stream) {
    const float* img = (const float*)d_in[0];
    const float* cap = (const float*)d_in[1];
    // d_in[2] = lens (unused)
    const float* Wg  = (const float*)d_in[3];
    const float* bg  = (const float*)d_in[4];
    const float* Wb  = (const float*)d_in[5];
    const float* bb  = (const float*)d_in[6];
    float* out = (float*)d_out;

    float* ws    = (float*)d_ws;
    float* ps    = ws;                     // 128*1024
    float* pss   = ps    + PRG * D;        // 128*1024
    float* img_q = pss   + PRG * D;        // 48*1024
    float* img_n = img_q + BI * D;         // 48*1024
    float* g1    = img_n + BI * D;         // 48*1024
    float* be    = g1    + BI * D;         // 48*1024
    float* mean  = be    + BI * D;         // 1024
    float* scale = mean  + D;              // 1024

    hipLaunchKernelGGL(k_stats, dim3(PRG + BI), dim3(256), 0, stream,
                       cap, img, ps, pss, img_q, img_n);
    hipLaunchKernelGGL(k_film,  dim3(520),      dim3(128), 0, stream,
                       img_q, Wg, bg, Wb, bb, ps, pss, g1, be, mean, scale);
    hipLaunchKernelGGL(k_fovea, dim3(768),      dim3(256), 0, stream,
                       cap, mean, scale, g1, be, img_n, out);
}

// Round 12
// 49.693 us; speedup vs baseline: 1.2492x; 1.2492x over previous
//
#include <hip/hip_runtime.h>
#include <math.h>

#define D     1024
#define D4    256     // D/4
#define BI    48
#define BC    48
#define RR    36
#define TT    40
#define EPSF  1e-5f
#define PRG   128     // cap-stat row groups
#define CROWS 15      // rows per group (128*15 = 1920)
#define L2E   1.4426950408889634f

typedef float f2 __attribute__((ext_vector_type(2)));

static __device__ __forceinline__ f2 f2max(f2 a, f2 b) {
    f2 r; r.x = fmaxf(a.x, b.x); r.y = fmaxf(a.y, b.y); return r;
}

// ---- K1: cap BN partial sums (blocks 0..127) + img_q/img_n (blocks 128..175)
__global__ __launch_bounds__(256) void k_stats(const float* __restrict__ cap,
                                               const float* __restrict__ img,
                                               float* __restrict__ ps,
                                               float* __restrict__ pss,
                                               float* __restrict__ img_q,
                                               float* __restrict__ img_n) {
    __shared__ float sw[4];
    int bx = blockIdx.x, tid = threadIdx.x;
    if (bx < PRG) {
        const float4* cap4 = (const float4*)cap;
        float4 s = {0,0,0,0}, ss = {0,0,0,0};
        int r0 = bx * CROWS;
#pragma unroll
        for (int r = 0; r < CROWS; ++r) {
            float4 v = cap4[(size_t)(r0 + r) * D4 + tid];
            s.x += v.x; s.y += v.y; s.z += v.z; s.w += v.w;
            ss.x += v.x*v.x; ss.y += v.y*v.y; ss.z += v.z*v.z; ss.w += v.w*v.w;
        }
        ((float4*)ps)[(size_t)bx * D4 + tid]  = s;
        ((float4*)pss)[(size_t)bx * D4 + tid] = ss;
    } else {
        int i = bx - PRG;
        const float4* img4 = (const float4*)img;
        float4 s = {0,0,0,0};
#pragma unroll
        for (int r = 0; r < RR; ++r) {
            float4 v = img4[((size_t)i * RR + r) * D4 + tid];
            s.x += v.x; s.y += v.y; s.z += v.z; s.w += v.w;
        }
        const float inv = 1.f / 36.f;
        float4 q = {s.x*inv, s.y*inv, s.z*inv, s.w*inv};
        ((float4*)img_q)[(size_t)i * D4 + tid] = q;
        float ssq = q.x*q.x + q.y*q.y + q.z*q.z + q.w*q.w;
#pragma unroll
        for (int off = 32; off; off >>= 1) ssq += __shfl_xor(ssq, off, 64);
        if ((tid & 63) == 0) sw[tid >> 6] = ssq;
        __syncthreads();
        float rinv = rsqrtf(sw[0] + sw[1] + sw[2] + sw[3]);
        float4 n = {q.x*rinv, q.y*rinv, q.z*rinv, q.w*rinv};
        ((float4*)img_n)[(size_t)i * D4 + tid] = n;
    }
}

// ---- K2: FiLM GEMMs (blocks 0..511: wave = 1 virtual row x 48 images)
//          + BN finalize (blocks 512..519). W rows prefetched upfront.
__global__ __launch_bounds__(256) void k_film(const float* __restrict__ img_q,
                                              const float* __restrict__ Wg,
                                              const float* __restrict__ bg,
                                              const float* __restrict__ Wb,
                                              const float* __restrict__ bb,
                                              const float* __restrict__ ps,
                                              const float* __restrict__ pss,
                                              float* __restrict__ g1,
                                              float* __restrict__ be,
                                              float* __restrict__ mean,
                                              float* __restrict__ scale) {
    __shared__ float smem[12544];            // 50176 B: lq4 (49152) / trbuf 4x3136
    float4* lq4 = (float4*)smem;
    int tid = threadIdx.x;

    if (blockIdx.x >= 512) {                 // ---- BN finalize: 8 blocks
        int bx2 = blockIdx.x - 512;          // 0..7
        int c32 = tid & 31;
        int col = bx2 * 32 + c32;            // float4 column 0..255
        int rs  = tid >> 5;                  // 0..7 row-subsets
        const float4* ps4  = (const float4*)ps;
        const float4* pss4 = (const float4*)pss;
        float4 s = {0,0,0,0}, q = {0,0,0,0};
#pragma unroll
        for (int gi = 0; gi < PRG / 8; ++gi) {
            int rg = rs * (PRG / 8) + gi;
            float4 a  = ps4[(size_t)rg * D4 + col];
            float4 b2 = pss4[(size_t)rg * D4 + col];
            s.x += a.x;  s.y += a.y;  s.z += a.z;  s.w += a.w;
            q.x += b2.x; q.y += b2.y; q.z += b2.z; q.w += b2.w;
        }
        float4* red = lq4;
        red[rs * 32 + c32]       = s;
        red[256 + rs * 32 + c32] = q;
        __syncthreads();
        if (rs == 0) {
            float4 S = {0,0,0,0}, Q = {0,0,0,0};
#pragma unroll
            for (int r2 = 0; r2 < 8; ++r2) {
                float4 a  = red[r2 * 32 + c32];
                float4 b2 = red[256 + r2 * 32 + c32];
                S.x += a.x;  S.y += a.y;  S.z += a.z;  S.w += a.w;
                Q.x += b2.x; Q.y += b2.y; Q.z += b2.z; Q.w += b2.w;
            }
            const float inv = 1.f / 1920.f;
            float4 M = {S.x*inv, S.y*inv, S.z*inv, S.w*inv};
            float4 SC;
            SC.x = rsqrtf(Q.x*inv - M.x*M.x + EPSF);
            SC.y = rsqrtf(Q.y*inv - M.y*M.y + EPSF);
            SC.z = rsqrtf(Q.z*inv - M.z*M.z + EPSF);
            SC.w = rsqrtf(Q.w*inv - M.w*M.w + EPSF);
            ((float4*)mean)[col]  = M;
            ((float4*)scale)[col] = SC;
        }
        return;
    }

    // ---- FiLM GEMM: wave = one virtual row (0..2047), all 48 images
    int wave = tid >> 6, lane = tid & 63;
    int row = blockIdx.x * 4 + wave;         // 0..2047
    int isbeta = row >> 10;
    int d = row & 1023;
    const float4* W4 = (const float4*)(isbeta ? Wb : Wg);

    // prefetch all 4 W chunks up front (latency overlaps kc0 staging)
    float4 wv[4];
#pragma unroll
    for (int kc = 0; kc < 4; ++kc)
        wv[kc] = W4[(size_t)d * D4 + kc * 64 + lane];

    float acc[BI];
#pragma unroll
    for (int i = 0; i < BI; ++i) acc[i] = 0.f;

    const float4* q4g = (const float4*)img_q;
#pragma unroll
    for (int kc = 0; kc < 4; ++kc) {
        __syncthreads();
        for (int idx = tid; idx < BI * 64; idx += 256) {
            int i = idx >> 6, kk = idx & 63;
            lq4[idx] = q4g[(size_t)i * D4 + kc * 64 + kk];
        }
        __syncthreads();
#pragma unroll
        for (int i = 0; i < BI; ++i) {
            float4 q = lq4[i * 64 + lane];
            acc[i] = fmaf(wv[kc].x, q.x, acc[i]);
            acc[i] = fmaf(wv[kc].y, q.y, acc[i]);
            acc[i] = fmaf(wv[kc].z, q.z, acc[i]);
            acc[i] = fmaf(wv[kc].w, q.w, acc[i]);
        }
    }
    // transpose-reduce: wave-private LDS region, stride 49 (conflict-free)
    __syncthreads();                         // all waves done reading lq4
    float* tr = smem + wave * 3136;          // 64*49 floats
#pragma unroll
    for (int i = 0; i < BI; ++i) tr[lane * 49 + i] = acc[i];
    float s0 = 0.f, s1 = 0.f, s2 = 0.f, s3 = 0.f;
#pragma unroll
    for (int l = 0; l < 64; l += 4) {
        s0 += tr[(l + 0) * 49 + lane];
        s1 += tr[(l + 1) * 49 + lane];
        s2 += tr[(l + 2) * 49 + lane];
        s3 += tr[(l + 3) * 49 + lane];
    }
    float sum = (s0 + s1) + (s2 + s3);
    if (lane < BI) {
        float badd = isbeta ? bb[d] : (bg[d] + 1.f);   // store 1+gamma
        float* outp = isbeta ? be : g1;
        outp[(size_t)lane * D + d] = sum + badd;
    }
}

// ---- K3: fused BN-normalize + Fovea + l2norm + cosine.
// 768 blocks = (b, 3 images); packed-f32 math (v_pk_*); XCD-bijective swizzle.
// log2e fold: y = x*log2e, e=2^y; vm/se carries a log2e factor (positive,
// same for all d of an (i,b) pair) -> cancels in the l2 normalization.
__global__ __launch_bounds__(256) void k_fovea(const float* __restrict__ cap,
                                               const float* __restrict__ mean,
                                               const float* __restrict__ scale,
                                               const float* __restrict__ g1,
                                               const float* __restrict__ be,
                                               const float* __restrict__ img_n,
                                               float* __restrict__ out) {
    int j = blockIdx.x;                      // 768 items
    int wg = (j & 7) * 96 + (j >> 3);        // bijective XCD swizzle (768 % 8 == 0)
    int b = wg >> 4, ig = wg & 15;
    int i0 = ig * 3;
    int tid = threadIdx.x;

    const float4* cap4 = (const float4*)cap;
    float4 m4  = ((const float4*)mean)[tid];
    float4 sc4 = ((const float4*)scale)[tid];
    f2 mm0 = {m4.x, m4.y},  mm1 = {m4.z, m4.w};
    f2 sc0 = {sc4.x, sc4.y}, sc1 = {sc4.z, sc4.w};

    // G2 = g*sc*L2E ; B2 = (bt - g*sc*m)*L2E
    f2 G2[3][2], B2[3][2];
#pragma unroll
    for (int u = 0; u < 3; ++u) {
        float4 t0 = ((const float4*)g1)[(size_t)(i0 + u) * D4 + tid];
        float4 u0 = ((const float4*)be)[(size_t)(i0 + u) * D4 + tid];
        f2 gg0 = {t0.x, t0.y}, gg1 = {t0.z, t0.w};
        f2 bt0 = {u0.x, u0.y}, bt1 = {u0.z, u0.w};
        f2 tt0 = gg0 * sc0, tt1 = gg1 * sc1;
        G2[u][0] = tt0 * L2E;
        G2[u][1] = tt1 * L2E;
        B2[u][0] = (bt0 - tt0 * mm0) * L2E;
        B2[u][1] = (bt1 - tt1 * mm1) * L2E;
    }
    f2 se[3][2], vm[3][2];
#pragma unroll
    for (int u = 0; u < 3; ++u)
#pragma unroll
        for (int c = 0; c < 2; ++c) {
            se[u][c] = (f2){0.f, 0.f};
            vm[u][c] = (f2){-INFINITY, -INFINITY};
        }

#pragma unroll 4
    for (int t = 0; t < TT; ++t) {
        float4 c4 = cap4[((size_t)b * TT + t) * D4 + tid];
        f2 cc0 = {c4.x, c4.y}, cc1 = {c4.z, c4.w};
#pragma unroll
        for (int u = 0; u < 3; ++u) {
            f2 y0 = cc0 * G2[u][0] + B2[u][0];
            f2 y1 = cc1 * G2[u][1] + B2[u][1];
            f2 e0, e1;
            e0.x = __builtin_amdgcn_exp2f(y0.x);
            e0.y = __builtin_amdgcn_exp2f(y0.y);
            e1.x = __builtin_amdgcn_exp2f(y1.x);
            e1.y = __builtin_amdgcn_exp2f(y1.y);
            se[u][0] += e0;
            se[u][1] += e1;
            vm[u][0] = f2max(vm[u][0], y0 * e0);
            vm[u][1] = f2max(vm[u][1], y1 * e1);
        }
    }
    float dd[3], sq[3];
#pragma unroll
    for (int u = 0; u < 3; ++u) {
        float4 nn = ((const float4*)img_n)[(size_t)(i0 + u) * D4 + tid];
        f2 r0, r1;
        r0.x = __builtin_amdgcn_rcpf(se[u][0].x);
        r0.y = __builtin_amdgcn_rcpf(se[u][0].y);
        r1.x = __builtin_amdgcn_rcpf(se[u][1].x);
        r1.y = __builtin_amdgcn_rcpf(se[u][1].y);
        f2 v0 = vm[u][0] * r0, v1 = vm[u][1] * r1;
        sq[u] = v0.x*v0.x + v0.y*v0.y + v1.x*v1.x + v1.y*v1.y;
        dd[u] = v0.x*nn.x + v0.y*nn.y + v1.x*nn.z + v1.y*nn.w;
    }
#pragma unroll
    for (int off = 32; off; off >>= 1) {
#pragma unroll
        for (int u = 0; u < 3; ++u) {
            dd[u] += __shfl_xor(dd[u], off, 64);
            sq[u] += __shfl_xor(sq[u], off, 64);
        }
    }
    __shared__ float rd[3][4], rq[3][4];     // [u][wave]
    int wave = tid >> 6, lane = tid & 63;
    if (lane == 0) {
#pragma unroll
        for (int u = 0; u < 3; ++u) { rd[u][wave] = dd[u]; rq[u][wave] = sq[u]; }
    }
    __syncthreads();
    if (tid < 3) {
        float td = rd[tid][0] + rd[tid][1] + rd[tid][2] + rd[tid][3];
        float ts = rq[tid][0] + rq[tid][1] + rq[tid][2] + rq[tid][3];
        out[(size_t)(i0 + tid) * BC + b] = td / sqrtf(ts);
    }
}

extern "C" void kernel_launch(void* const* d_in, const int* in_sizes, int n_in,
                              void* d_out, int out_size, void* d_ws, size_t ws_size,
                              hipStream_t stream) {
    const float* img = (const float*)d_in[0];
    const float* cap = (const float*)d_in[1];
    // d_in[2] = lens (unused)
    const float* Wg  = (const float*)d_in[3];
    const float* bg  = (const float*)d_in[4];
    const float* Wb  = (const float*)d_in[5];
    const float* bb  = (const float*)d_in[6];
    float* out = (float*)d_out;

    float* ws    = (float*)d_ws;
    float* ps    = ws;                     // 128*1024
    float* pss   = ps    + PRG * D;        // 128*1024
    float* img_q = pss   + PRG * D;        // 48*1024
    float* img_n = img_q + BI * D;         // 48*1024
    float* g1    = img_n + BI * D;         // 48*1024
    float* be    = g1    + BI * D;         // 48*1024
    float* mean  = be    + BI * D;         // 1024
    float* scale = mean  + D;              // 1024

    hipLaunchKernelGGL(k_stats, dim3(PRG + BI), dim3(256), 0, stream,
                       cap, img, ps, pss, img_q, img_n);
    hipLaunchKernelGGL(k_film,  dim3(520),      dim3(256), 0, stream,
                       img_q, Wg, bg, Wb, bb, ps, pss, g1, be, mean, scale);
    hipLaunchKernelGGL(k_fovea, dim3(768),      dim3(256), 0, stream,
                       cap, mean, scale, g1, be, img_n, out);
}

// Round 13
// 45.573 us; speedup vs baseline: 1.3622x; 1.0904x over previous
//
#include <hip/hip_runtime.h>
#include <math.h>

#define D     1024
#define D4    256     // D/4
#define BI    48
#define BC    48
#define RR    36
#define TT    40
#define EPSF  1e-5f
#define PRG   128     // cap-stat row groups
#define CROWS 15      // rows per group (128*15 = 1920)
#define L2E   1.4426950408889634f

typedef float f2 __attribute__((ext_vector_type(2)));
typedef _Float16 h2 __attribute__((ext_vector_type(2)));

static __device__ __forceinline__ f2 f2max(f2 a, f2 b) {
    f2 r; r.x = fmaxf(a.x, b.x); r.y = fmaxf(a.y, b.y); return r;
}
static __device__ __forceinline__ h2 bch2(unsigned u) {
    union { unsigned u; h2 h; } c; c.u = u; return c.h;
}
static __device__ __forceinline__ unsigned bcu(h2 h) {
    union { h2 h; unsigned u; } c; c.h = h; return c.u;
}

// ---- K1: cap BN partial sums (blocks 0..127) + img_q/img_n (blocks 128..175)
__global__ __launch_bounds__(256) void k_stats(const float* __restrict__ cap,
                                               const float* __restrict__ img,
                                               float* __restrict__ ps,
                                               float* __restrict__ pss,
                                               float* __restrict__ img_q,
                                               float* __restrict__ img_n) {
    __shared__ float sw[4];
    int bx = blockIdx.x, tid = threadIdx.x;
    if (bx < PRG) {
        const float4* cap4 = (const float4*)cap;
        float4 s = {0,0,0,0}, ss = {0,0,0,0};
        int r0 = bx * CROWS;
#pragma unroll
        for (int r = 0; r < CROWS; ++r) {
            float4 v = cap4[(size_t)(r0 + r) * D4 + tid];
            s.x += v.x; s.y += v.y; s.z += v.z; s.w += v.w;
            ss.x += v.x*v.x; ss.y += v.y*v.y; ss.z += v.z*v.z; ss.w += v.w*v.w;
        }
        ((float4*)ps)[(size_t)bx * D4 + tid]  = s;
        ((float4*)pss)[(size_t)bx * D4 + tid] = ss;
    } else {
        int i = bx - PRG;
        const float4* img4 = (const float4*)img;
        float4 s = {0,0,0,0};
#pragma unroll
        for (int r = 0; r < RR; ++r) {
            float4 v = img4[((size_t)i * RR + r) * D4 + tid];
            s.x += v.x; s.y += v.y; s.z += v.z; s.w += v.w;
        }
        const float inv = 1.f / 36.f;
        float4 q = {s.x*inv, s.y*inv, s.z*inv, s.w*inv};
        ((float4*)img_q)[(size_t)i * D4 + tid] = q;
        float ssq = q.x*q.x + q.y*q.y + q.z*q.z + q.w*q.w;
#pragma unroll
        for (int off = 32; off; off >>= 1) ssq += __shfl_xor(ssq, off, 64);
        if ((tid & 63) == 0) sw[tid >> 6] = ssq;
        __syncthreads();
        float rinv = rsqrtf(sw[0] + sw[1] + sw[2] + sw[3]);
        float4 n = {q.x*rinv, q.y*rinv, q.z*rinv, q.w*rinv};
        ((float4*)img_n)[(size_t)i * D4 + tid] = n;
    }
}

// ---- K2: FiLM GEMMs (blocks 0..511: wave = 1 row x 48 images, f16 LDS +
//          v_dot2_f32_f16) + BN finalize (blocks 512..519).
// q staged as f16: one ds_read_b128 = 8 k -> main-loop DS instrs halved vs f32.
__global__ __launch_bounds__(256) void k_film(const float* __restrict__ img_q,
                                              const float* __restrict__ Wg,
                                              const float* __restrict__ bg,
                                              const float* __restrict__ Wb,
                                              const float* __restrict__ bb,
                                              const float* __restrict__ ps,
                                              const float* __restrict__ pss,
                                              float* __restrict__ g1,
                                              float* __restrict__ be,
                                              float* __restrict__ mean,
                                              float* __restrict__ scale) {
    __shared__ float smem[12544];            // 50176 B: f16 lq (48KB) / trbuf 4x3136
    int tid = threadIdx.x;

    if (blockIdx.x >= 512) {                 // ---- BN finalize: 8 blocks
        int bx2 = blockIdx.x - 512;          // 0..7
        int c32 = tid & 31;
        int col = bx2 * 32 + c32;            // float4 column 0..255
        int rs  = tid >> 5;                  // 0..7 row-subsets
        const float4* ps4  = (const float4*)ps;
        const float4* pss4 = (const float4*)pss;
        float4 s = {0,0,0,0}, q = {0,0,0,0};
#pragma unroll
        for (int gi = 0; gi < PRG / 8; ++gi) {
            int rg = rs * (PRG / 8) + gi;
            float4 a  = ps4[(size_t)rg * D4 + col];
            float4 b2 = pss4[(size_t)rg * D4 + col];
            s.x += a.x;  s.y += a.y;  s.z += a.z;  s.w += a.w;
            q.x += b2.x; q.y += b2.y; q.z += b2.z; q.w += b2.w;
        }
        float4* red = (float4*)smem;
        red[rs * 32 + c32]       = s;
        red[256 + rs * 32 + c32] = q;
        __syncthreads();
        if (rs == 0) {
            float4 S = {0,0,0,0}, Q = {0,0,0,0};
#pragma unroll
            for (int r2 = 0; r2 < 8; ++r2) {
                float4 a  = red[r2 * 32 + c32];
                float4 b2 = red[256 + r2 * 32 + c32];
                S.x += a.x;  S.y += a.y;  S.z += a.z;  S.w += a.w;
                Q.x += b2.x; Q.y += b2.y; Q.z += b2.z; Q.w += b2.w;
            }
            const float inv = 1.f / 1920.f;
            float4 M = {S.x*inv, S.y*inv, S.z*inv, S.w*inv};
            float4 SC;
            SC.x = rsqrtf(Q.x*inv - M.x*M.x + EPSF);
            SC.y = rsqrtf(Q.y*inv - M.y*M.y + EPSF);
            SC.z = rsqrtf(Q.z*inv - M.z*M.z + EPSF);
            SC.w = rsqrtf(Q.w*inv - M.w*M.w + EPSF);
            ((float4*)mean)[col]  = M;
            ((float4*)scale)[col] = SC;
        }
        return;
    }

    // ---- FiLM GEMM: wave = one virtual row (0..2047), all 48 images
    int wave = tid >> 6, lane = tid & 63;
    int row = blockIdx.x * 4 + wave;         // 0..2047
    int isbeta = row >> 10;
    int d = row & 1023;
    const float4* W4 = (const float4*)(isbeta ? Wb : Wg);

    // prefetch W: lane owns k = half*512 + lane*8 .. +7 (2 float4 per half)
    // convert once to h2 pairs for fdot2
    h2 wh[2][4];
#pragma unroll
    for (int half = 0; half < 2; ++half) {
#pragma unroll
        for (int j = 0; j < 2; ++j) {
            float4 w = W4[(size_t)d * D4 + half * 128 + lane * 2 + j];
            h2 a; a.x = (_Float16)w.x; a.y = (_Float16)w.y;
            h2 b; b.x = (_Float16)w.z; b.y = (_Float16)w.w;
            wh[half][j * 2 + 0] = a;
            wh[half][j * 2 + 1] = b;
        }
    }

    float acc[BI];
#pragma unroll
    for (int i = 0; i < BI; ++i) acc[i] = 0.f;

    const float4* q4g = (const float4*)img_q;
    uint2* lqh2 = (uint2*)smem;              // staging view (8B = 4 f16)
    const uint4* lqh4 = (const uint4*)smem;  // read view (16B = 8 f16)
#pragma unroll
    for (int half = 0; half < 2; ++half) {
        __syncthreads();
        // stage 48 img x 512 k as f16: flat idx over (img, j<128) float4s
        for (int idx = tid; idx < BI * 128; idx += 256) {
            int img = idx >> 7, j = idx & 127;
            float4 v = q4g[(size_t)img * D4 + half * 128 + j];
            h2 a; a.x = (_Float16)v.x; a.y = (_Float16)v.y;
            h2 b; b.x = (_Float16)v.z; b.y = (_Float16)v.w;
            uint2 w; w.x = bcu(a); w.y = bcu(b);
            lqh2[img * 128 + j] = w;         // byte: img*1024 + j*8
        }
        __syncthreads();
#pragma unroll
        for (int i = 0; i < BI; ++i) {
            uint4 r = lqh4[i * 64 + lane];   // 8 k of image i (contiguous 1KB/wave)
            acc[i] = __builtin_amdgcn_fdot2(wh[half][0], bch2(r.x), acc[i], false);
            acc[i] = __builtin_amdgcn_fdot2(wh[half][1], bch2(r.y), acc[i], false);
            acc[i] = __builtin_amdgcn_fdot2(wh[half][2], bch2(r.z), acc[i], false);
            acc[i] = __builtin_amdgcn_fdot2(wh[half][3], bch2(r.w), acc[i], false);
        }
    }
    // transpose-reduce: wave-private LDS region, stride 49 (conflict-free)
    __syncthreads();                         // all waves done reading lq
    float* tr = smem + wave * 3136;          // 64*49 floats
#pragma unroll
    for (int i = 0; i < BI; ++i) tr[lane * 49 + i] = acc[i];
    float s0 = 0.f, s1 = 0.f, s2 = 0.f, s3 = 0.f;
#pragma unroll
    for (int l = 0; l < 64; l += 4) {
        s0 += tr[(l + 0) * 49 + lane];
        s1 += tr[(l + 1) * 49 + lane];
        s2 += tr[(l + 2) * 49 + lane];
        s3 += tr[(l + 3) * 49 + lane];
    }
    float sum = (s0 + s1) + (s2 + s3);
    if (lane < BI) {
        float badd = isbeta ? bb[d] : (bg[d] + 1.f);   // store 1+gamma
        float* outp = isbeta ? be : g1;
        outp[(size_t)lane * D + d] = sum + badd;
    }
}

// ---- K3: fused BN-normalize + Fovea + l2norm + cosine. (unchanged from R12)
// 768 blocks = (b, 3 images); packed-f32 math; XCD-bijective swizzle.
// log2e fold: y = x*log2e, e=2^y; vm/se carries a log2e factor (positive,
// same for all d of an (i,b) pair) -> cancels in the l2 normalization.
__global__ __launch_bounds__(256) void k_fovea(const float* __restrict__ cap,
                                               const float* __restrict__ mean,
                                               const float* __restrict__ scale,
                                               const float* __restrict__ g1,
                                               const float* __restrict__ be,
                                               const float* __restrict__ img_n,
                                               float* __restrict__ out) {
    int j = blockIdx.x;                      // 768 items
    int wg = (j & 7) * 96 + (j >> 3);        // bijective XCD swizzle (768 % 8 == 0)
    int b = wg >> 4, ig = wg & 15;
    int i0 = ig * 3;
    int tid = threadIdx.x;

    const float4* cap4 = (const float4*)cap;
    float4 m4  = ((const float4*)mean)[tid];
    float4 sc4 = ((const float4*)scale)[tid];
    f2 mm0 = {m4.x, m4.y},  mm1 = {m4.z, m4.w};
    f2 sc0 = {sc4.x, sc4.y}, sc1 = {sc4.z, sc4.w};

    // G2 = g*sc*L2E ; B2 = (bt - g*sc*m)*L2E
    f2 G2[3][2], B2[3][2];
#pragma unroll
    for (int u = 0; u < 3; ++u) {
        float4 t0 = ((const float4*)g1)[(size_t)(i0 + u) * D4 + tid];
        float4 u0 = ((const float4*)be)[(size_t)(i0 + u) * D4 + tid];
        f2 gg0 = {t0.x, t0.y}, gg1 = {t0.z, t0.w};
        f2 bt0 = {u0.x, u0.y}, bt1 = {u0.z, u0.w};
        f2 tt0 = gg0 * sc0, tt1 = gg1 * sc1;
        G2[u][0] = tt0 * L2E;
        G2[u][1] = tt1 * L2E;
        B2[u][0] = (bt0 - tt0 * mm0) * L2E;
        B2[u][1] = (bt1 - tt1 * mm1) * L2E;
    }
    f2 se[3][2], vm[3][2];
#pragma unroll
    for (int u = 0; u < 3; ++u)
#pragma unroll
        for (int c = 0; c < 2; ++c) {
            se[u][c] = (f2){0.f, 0.f};
            vm[u][c] = (f2){-INFINITY, -INFINITY};
        }

#pragma unroll 4
    for (int t = 0; t < TT; ++t) {
        float4 c4 = cap4[((size_t)b * TT + t) * D4 + tid];
        f2 cc0 = {c4.x, c4.y}, cc1 = {c4.z, c4.w};
#pragma unroll
        for (int u = 0; u < 3; ++u) {
            f2 y0 = cc0 * G2[u][0] + B2[u][0];
            f2 y1 = cc1 * G2[u][1] + B2[u][1];
            f2 e0, e1;
            e0.x = __builtin_amdgcn_exp2f(y0.x);
            e0.y = __builtin_amdgcn_exp2f(y0.y);
            e1.x = __builtin_amdgcn_exp2f(y1.x);
            e1.y = __builtin_amdgcn_exp2f(y1.y);
            se[u][0] += e0;
            se[u][1] += e1;
            vm[u][0] = f2max(vm[u][0], y0 * e0);
            vm[u][1] = f2max(vm[u][1], y1 * e1);
        }
    }
    float dd[3], sq[3];
#pragma unroll
    for (int u = 0; u < 3; ++u) {
        float4 nn = ((const float4*)img_n)[(size_t)(i0 + u) * D4 + tid];
        f2 r0, r1;
        r0.x = __builtin_amdgcn_rcpf(se[u][0].x);
        r0.y = __builtin_amdgcn_rcpf(se[u][0].y);
        r1.x = __builtin_amdgcn_rcpf(se[u][1].x);
        r1.y = __builtin_amdgcn_rcpf(se[u][1].y);
        f2 v0 = vm[u][0] * r0, v1 = vm[u][1] * r1;
        sq[u] = v0.x*v0.x + v0.y*v0.y + v1.x*v1.x + v1.y*v1.y;
        dd[u] = v0.x*nn.x + v0.y*nn.y + v1.x*nn.z + v1.y*nn.w;
    }
#pragma unroll
    for (int off = 32; off; off >>= 1) {
#pragma unroll
        for (int u = 0; u < 3; ++u) {
            dd[u] += __shfl_xor(dd[u], off, 64);
            sq[u] += __shfl_xor(sq[u], off, 64);
        }
    }
    __shared__ float rd[3][4], rq[3][4];     // [u][wave]
    int wave = tid >> 6, lane = tid & 63;
    if (lane == 0) {
#pragma unroll
        for (int u = 0; u < 3; ++u) { rd[u][wave] = dd[u]; rq[u][wave] = sq[u]; }
    }
    __syncthreads();
    if (tid < 3) {
        float td = rd[tid][0] + rd[tid][1] + rd[tid][2] + rd[tid][3];
        float ts = rq[tid][0] + rq[tid][1] + rq[tid][2] + rq[tid][3];
        out[(size_t)(i0 + tid) * BC + b] = td / sqrtf(ts);
    }
}

extern "C" void kernel_launch(void* const* d_in, const int* in_sizes, int n_in,
                              void* d_out, int out_size, void* d_ws, size_t ws_size,
                              hipStream_t stream) {
    const float* img = (const float*)d_in[0];
    const float* cap = (const float*)d_in[1];
    // d_in[2] = lens (unused)
    const float* Wg  = (const float*)d_in[3];
    const float* bg  = (const float*)d_in[4];
    const float* Wb  = (const float*)d_in[5];
    const float* bb  = (const float*)d_in[6];
    float* out = (float*)d_out;

    float* ws    = (float*)d_ws;
    float* ps    = ws;                     // 128*1024
    float* pss   = ps    + PRG * D;        // 128*1024
    float* img_q = pss   + PRG * D;        // 48*1024
    float* img_n = img_q + BI * D;         // 48*1024
    float* g1    = img_n + BI * D;         // 48*1024
    float* be    = g1    + BI * D;         // 48*1024
    float* mean  = be    + BI * D;         // 1024
    float* scale = mean  + D;              // 1024

    hipLaunchKernelGGL(k_stats, dim3(PRG + BI), dim3(256), 0, stream,
                       cap, img, ps, pss, img_q, img_n);
    hipLaunchKernelGGL(k_film,  dim3(520),      dim3(256), 0, stream,
                       img_q, Wg, bg, Wb, bb, ps, pss, g1, be, mean, scale);
    hipLaunchKernelGGL(k_fovea, dim3(768),      dim3(256), 0, stream,
                       cap, mean, scale, g1, be, img_n, out);
}

// Round 14
// 39.717 us; speedup vs baseline: 1.5630x; 1.1474x over previous
//
#include <hip/hip_runtime.h>
#include <math.h>

#define D     1024
#define D4    256     // D/4
#define BI    48
#define BC    48
#define RR    36
#define TT    40
#define EPSF  1e-5f
#define PRG   128     // cap-stat row groups
#define CROWS 15      // rows per group (128*15 = 1920)
#define L2E   1.4426950408889634f

typedef float f2 __attribute__((ext_vector_type(2)));
typedef _Float16 h2 __attribute__((ext_vector_type(2)));

static __device__ __forceinline__ f2 f2max(f2 a, f2 b) {
    f2 r; r.x = fmaxf(a.x, b.x); r.y = fmaxf(a.y, b.y); return r;
}
static __device__ __forceinline__ h2 bch2(unsigned u) {
    union { unsigned u; h2 h; } c; c.u = u; return c.h;
}
static __device__ __forceinline__ unsigned bcu(h2 h) {
    union { h2 h; unsigned u; } c; c.h = h; return c.u;
}

// ---- K1: cap BN partial sums (blocks 0..127) + img_q(f16)/img_n (128..175)
__global__ __launch_bounds__(256) void k_stats(const float* __restrict__ cap,
                                               const float* __restrict__ img,
                                               float* __restrict__ ps,
                                               float* __restrict__ pss,
                                               unsigned* __restrict__ img_qh,
                                               float* __restrict__ img_n) {
    __shared__ float sw[4];
    int bx = blockIdx.x, tid = threadIdx.x;
    if (bx < PRG) {
        const float4* cap4 = (const float4*)cap;
        float4 s = {0,0,0,0}, ss = {0,0,0,0};
        int r0 = bx * CROWS;
#pragma unroll
        for (int r = 0; r < CROWS; ++r) {
            float4 v = cap4[(size_t)(r0 + r) * D4 + tid];
            s.x += v.x; s.y += v.y; s.z += v.z; s.w += v.w;
            ss.x += v.x*v.x; ss.y += v.y*v.y; ss.z += v.z*v.z; ss.w += v.w*v.w;
        }
        ((float4*)ps)[(size_t)bx * D4 + tid]  = s;
        ((float4*)pss)[(size_t)bx * D4 + tid] = ss;
    } else {
        int i = bx - PRG;
        const float4* img4 = (const float4*)img;
        float4 s = {0,0,0,0};
#pragma unroll
        for (int r = 0; r < RR; ++r) {
            float4 v = img4[((size_t)i * RR + r) * D4 + tid];
            s.x += v.x; s.y += v.y; s.z += v.z; s.w += v.w;
        }
        const float inv = 1.f / 36.f;
        float4 q = {s.x*inv, s.y*inv, s.z*inv, s.w*inv};
        // f16 img_q for the film GEMM (RN cast, same rounding film used before)
        h2 a; a.x = (_Float16)q.x; a.y = (_Float16)q.y;
        h2 b; b.x = (_Float16)q.z; b.y = (_Float16)q.w;
        uint2 w; w.x = bcu(a); w.y = bcu(b);
        ((uint2*)img_qh)[(size_t)i * D4 + tid] = w;
        float ssq = q.x*q.x + q.y*q.y + q.z*q.z + q.w*q.w;
#pragma unroll
        for (int off = 32; off; off >>= 1) ssq += __shfl_xor(ssq, off, 64);
        if ((tid & 63) == 0) sw[tid >> 6] = ssq;
        __syncthreads();
        float rinv = rsqrtf(sw[0] + sw[1] + sw[2] + sw[3]);
        float4 n = {q.x*rinv, q.y*rinv, q.z*rinv, q.w*rinv};
        ((float4*)img_n)[(size_t)i * D4 + tid] = n;
    }
}

// ---- K2: FiLM GEMMs (blocks 0..511: wave = 1 row x 48 images, f16 LDS +
//          v_dot2_f32_f16; img_q pre-converted) + BN finalize (512..519).
__global__ __launch_bounds__(256) void k_film(const unsigned* __restrict__ img_qh,
                                              const float* __restrict__ Wg,
                                              const float* __restrict__ bg,
                                              const float* __restrict__ Wb,
                                              const float* __restrict__ bb,
                                              const float* __restrict__ ps,
                                              const float* __restrict__ pss,
                                              float* __restrict__ g1,
                                              float* __restrict__ be,
                                              float* __restrict__ mean,
                                              float* __restrict__ scale) {
    __shared__ float smem[12544];            // 50176 B: f16 lq (48KB) / trbuf 4x3136
    int tid = threadIdx.x;

    if (blockIdx.x >= 512) {                 // ---- BN finalize: 8 blocks
        int bx2 = blockIdx.x - 512;          // 0..7
        int c32 = tid & 31;
        int col = bx2 * 32 + c32;            // float4 column 0..255
        int rs  = tid >> 5;                  // 0..7 row-subsets
        const float4* ps4  = (const float4*)ps;
        const float4* pss4 = (const float4*)pss;
        float4 s = {0,0,0,0}, q = {0,0,0,0};
#pragma unroll
        for (int gi = 0; gi < PRG / 8; ++gi) {
            int rg = rs * (PRG / 8) + gi;
            float4 a  = ps4[(size_t)rg * D4 + col];
            float4 b2 = pss4[(size_t)rg * D4 + col];
            s.x += a.x;  s.y += a.y;  s.z += a.z;  s.w += a.w;
            q.x += b2.x; q.y += b2.y; q.z += b2.z; q.w += b2.w;
        }
        float4* red = (float4*)smem;
        red[rs * 32 + c32]       = s;
        red[256 + rs * 32 + c32] = q;
        __syncthreads();
        if (rs == 0) {
            float4 S = {0,0,0,0}, Q = {0,0,0,0};
#pragma unroll
            for (int r2 = 0; r2 < 8; ++r2) {
                float4 a  = red[r2 * 32 + c32];
                float4 b2 = red[256 + r2 * 32 + c32];
                S.x += a.x;  S.y += a.y;  S.z += a.z;  S.w += a.w;
                Q.x += b2.x; Q.y += b2.y; Q.z += b2.z; Q.w += b2.w;
            }
            const float inv = 1.f / 1920.f;
            float4 M = {S.x*inv, S.y*inv, S.z*inv, S.w*inv};
            float4 SC;
            SC.x = rsqrtf(Q.x*inv - M.x*M.x + EPSF);
            SC.y = rsqrtf(Q.y*inv - M.y*M.y + EPSF);
            SC.z = rsqrtf(Q.z*inv - M.z*M.z + EPSF);
            SC.w = rsqrtf(Q.w*inv - M.w*M.w + EPSF);
            ((float4*)mean)[col]  = M;
            ((float4*)scale)[col] = SC;
        }
        return;
    }

    // ---- FiLM GEMM: wave = one virtual row (0..2047), all 48 images
    int wave = tid >> 6, lane = tid & 63;
    int row = blockIdx.x * 4 + wave;         // 0..2047
    int isbeta = row >> 10;
    int d = row & 1023;
    const float4* W4 = (const float4*)(isbeta ? Wb : Wg);

    // prefetch W: lane owns k = half*512 + lane*8 .. +7 (2 float4 per half)
    h2 wh[2][4];
#pragma unroll
    for (int half = 0; half < 2; ++half) {
#pragma unroll
        for (int j = 0; j < 2; ++j) {
            float4 w = W4[(size_t)d * D4 + half * 128 + lane * 2 + j];
            h2 a; a.x = (_Float16)w.x; a.y = (_Float16)w.y;
            h2 b; b.x = (_Float16)w.z; b.y = (_Float16)w.w;
            wh[half][j * 2 + 0] = a;
            wh[half][j * 2 + 1] = b;
        }
    }

    float acc[BI];
#pragma unroll
    for (int i = 0; i < BI; ++i) acc[i] = 0.f;

    const uint4* qh4 = (const uint4*)img_qh; // [i][128] uint4 = 8 f16 each
    uint4* lq_st = (uint4*)smem;             // staging view
    const uint4* lqh4 = (const uint4*)smem;  // read view
#pragma unroll
    for (int half = 0; half < 2; ++half) {
        __syncthreads();
        // stage 48 img x 512 k (f16, raw copy): 3072 uint4, 12 per thread
        for (int idx = tid; idx < BI * 64; idx += 256) {
            int img = idx >> 6, j = idx & 63;
            lq_st[idx] = qh4[(size_t)img * 128 + half * 64 + j];
        }
        __syncthreads();
#pragma unroll
        for (int i = 0; i < BI; ++i) {
            uint4 r = lqh4[i * 64 + lane];   // 8 k of image i
            acc[i] = __builtin_amdgcn_fdot2(wh[half][0], bch2(r.x), acc[i], false);
            acc[i] = __builtin_amdgcn_fdot2(wh[half][1], bch2(r.y), acc[i], false);
            acc[i] = __builtin_amdgcn_fdot2(wh[half][2], bch2(r.z), acc[i], false);
            acc[i] = __builtin_amdgcn_fdot2(wh[half][3], bch2(r.w), acc[i], false);
        }
    }
    // transpose-reduce: wave-private LDS region, stride 49 (conflict-free)
    __syncthreads();                         // all waves done reading lq
    float* tr = smem + wave * 3136;          // 64*49 floats
#pragma unroll
    for (int i = 0; i < BI; ++i) tr[lane * 49 + i] = acc[i];
    float s0 = 0.f, s1 = 0.f, s2 = 0.f, s3 = 0.f;
#pragma unroll
    for (int l = 0; l < 64; l += 4) {
        s0 += tr[(l + 0) * 49 + lane];
        s1 += tr[(l + 1) * 49 + lane];
        s2 += tr[(l + 2) * 49 + lane];
        s3 += tr[(l + 3) * 49 + lane];
    }
    float sum = (s0 + s1) + (s2 + s3);
    if (lane < BI) {
        float badd = isbeta ? bb[d] : (bg[d] + 1.f);   // store 1+gamma
        float* outp = isbeta ? be : g1;
        outp[(size_t)lane * D + d] = sum + badd;
    }
}

// ---- K3: fused BN-normalize + Fovea + l2norm + cosine. (unchanged from R13)
// 768 blocks = (b, 3 images); packed-f32 math; XCD-bijective swizzle.
// log2e fold: y = x*log2e, e=2^y; vm/se carries a log2e factor (positive,
// same for all d of an (i,b) pair) -> cancels in the l2 normalization.
__global__ __launch_bounds__(256) void k_fovea(const float* __restrict__ cap,
                                               const float* __restrict__ mean,
                                               const float* __restrict__ scale,
                                               const float* __restrict__ g1,
                                               const float* __restrict__ be,
                                               const float* __restrict__ img_n,
                                               float* __restrict__ out) {
    int j = blockIdx.x;                      // 768 items
    int wg = (j & 7) * 96 + (j >> 3);        // bijective XCD swizzle (768 % 8 == 0)
    int b = wg >> 4, ig = wg & 15;
    int i0 = ig * 3;
    int tid = threadIdx.x;

    const float4* cap4 = (const float4*)cap;
    float4 m4  = ((const float4*)mean)[tid];
    float4 sc4 = ((const float4*)scale)[tid];
    f2 mm0 = {m4.x, m4.y},  mm1 = {m4.z, m4.w};
    f2 sc0 = {sc4.x, sc4.y}, sc1 = {sc4.z, sc4.w};

    // G2 = g*sc*L2E ; B2 = (bt - g*sc*m)*L2E
    f2 G2[3][2], B2[3][2];
#pragma unroll
    for (int u = 0; u < 3; ++u) {
        float4 t0 = ((const float4*)g1)[(size_t)(i0 + u) * D4 + tid];
        float4 u0 = ((const float4*)be)[(size_t)(i0 + u) * D4 + tid];
        f2 gg0 = {t0.x, t0.y}, gg1 = {t0.z, t0.w};
        f2 bt0 = {u0.x, u0.y}, bt1 = {u0.z, u0.w};
        f2 tt0 = gg0 * sc0, tt1 = gg1 * sc1;
        G2[u][0] = tt0 * L2E;
        G2[u][1] = tt1 * L2E;
        B2[u][0] = (bt0 - tt0 * mm0) * L2E;
        B2[u][1] = (bt1 - tt1 * mm1) * L2E;
    }
    f2 se[3][2], vm[3][2];
#pragma unroll
    for (int u = 0; u < 3; ++u)
#pragma unroll
        for (int c = 0; c < 2; ++c) {
            se[u][c] = (f2){0.f, 0.f};
            vm[u][c] = (f2){-INFINITY, -INFINITY};
        }

#pragma unroll 4
    for (int t = 0; t < TT; ++t) {
        float4 c4 = cap4[((size_t)b * TT + t) * D4 + tid];
        f2 cc0 = {c4.x, c4.y}, cc1 = {c4.z, c4.w};
#pragma unroll
        for (int u = 0; u < 3; ++u) {
            f2 y0 = cc0 * G2[u][0] + B2[u][0];
            f2 y1 = cc1 * G2[u][1] + B2[u][1];
            f2 e0, e1;
            e0.x = __builtin_amdgcn_exp2f(y0.x);
            e0.y = __builtin_amdgcn_exp2f(y0.y);
            e1.x = __builtin_amdgcn_exp2f(y1.x);
            e1.y = __builtin_amdgcn_exp2f(y1.y);
            se[u][0] += e0;
            se[u][1] += e1;
            vm[u][0] = f2max(vm[u][0], y0 * e0);
            vm[u][1] = f2max(vm[u][1], y1 * e1);
        }
    }
    float dd[3], sq[3];
#pragma unroll
    for (int u = 0; u < 3; ++u) {
        float4 nn = ((const float4*)img_n)[(size_t)(i0 + u) * D4 + tid];
        f2 r0, r1;
        r0.x = __builtin_amdgcn_rcpf(se[u][0].x);
        r0.y = __builtin_amdgcn_rcpf(se[u][0].y);
        r1.x = __builtin_amdgcn_rcpf(se[u][1].x);
        r1.y = __builtin_amdgcn_rcpf(se[u][1].y);
        f2 v0 = vm[u][0] * r0, v1 = vm[u][1] * r1;
        sq[u] = v0.x*v0.x + v0.y*v0.y + v1.x*v1.x + v1.y*v1.y;
        dd[u] = v0.x*nn.x + v0.y*nn.y + v1.x*nn.z + v1.y*nn.w;
    }
#pragma unroll
    for (int off = 32; off; off >>= 1) {
#pragma unroll
        for (int u = 0; u < 3; ++u) {
            dd[u] += __shfl_xor(dd[u], off, 64);
            sq[u] += __shfl_xor(sq[u], off, 64);
        }
    }
    __shared__ float rd[3][4], rq[3][4];     // [u][wave]
    int wave = tid >> 6, lane = tid & 63;
    if (lane == 0) {
#pragma unroll
        for (int u = 0; u < 3; ++u) { rd[u][wave] = dd[u]; rq[u][wave] = sq[u]; }
    }
    __syncthreads();
    if (tid < 3) {
        float td = rd[tid][0] + rd[tid][1] + rd[tid][2] + rd[tid][3];
        float ts = rq[tid][0] + rq[tid][1] + rq[tid][2] + rq[tid][3];
        out[(size_t)(i0 + tid) * BC + b] = td / sqrtf(ts);
    }
}

extern "C" void kernel_launch(void* const* d_in, const int* in_sizes, int n_in,
                              void* d_out, int out_size, void* d_ws, size_t ws_size,
                              hipStream_t stream) {
    const float* img = (const float*)d_in[0];
    const float* cap = (const float*)d_in[1];
    // d_in[2] = lens (unused)
    const float* Wg  = (const float*)d_in[3];
    const float* bg  = (const float*)d_in[4];
    const float* Wb  = (const float*)d_in[5];
    const float* bb  = (const float*)d_in[6];
    float* out = (float*)d_out;

    float* ws     = (float*)d_ws;
    float* ps     = ws;                    // 128*1024
    float* pss    = ps     + PRG * D;      // 128*1024
    float* img_qf = pss    + PRG * D;      // 48*1024 (f16 stored in first half)
    float* img_n  = img_qf + BI * D;       // 48*1024
    float* g1     = img_n  + BI * D;       // 48*1024
    float* be     = g1     + BI * D;       // 48*1024
    float* mean   = be     + BI * D;       // 1024
    float* scale  = mean   + D;            // 1024
    unsigned* img_qh = (unsigned*)img_qf;  // 48*1024 f16 = 96 KB

    hipLaunchKernelGGL(k_stats, dim3(PRG + BI), dim3(256), 0, stream,
                       cap, img, ps, pss, img_qh, img_n);
    hipLaunchKernelGGL(k_film,  dim3(520),      dim3(256), 0, stream,
                       img_qh, Wg, bg, Wb, bb, ps, pss, g1, be, mean, scale);
    hipLaunchKernelGGL(k_fovea, dim3(768),      dim3(256), 0, stream,
                       cap, mean, scale, g1, be, img_n, out);
}

// Round 15
// 38.857 us; speedup vs baseline: 1.5976x; 1.0222x over previous
//
#include <hip/hip_runtime.h>
#include <math.h>

#define D     1024
#define D4    256     // D/4
#define BI    48
#define BC    48
#define RR    36
#define TT    40
#define EPSF  1e-5f
#define PRG   160     // cap-stat row groups (12 rows each)
#define IMGB  96      // img blocks: 2 per image (channel halves)
#define L2E   1.4426950408889634f

typedef float f2 __attribute__((ext_vector_type(2)));
typedef _Float16 h2 __attribute__((ext_vector_type(2)));

static __device__ __forceinline__ f2 f2max(f2 a, f2 b) {
    f2 r; r.x = fmaxf(a.x, b.x); r.y = fmaxf(a.y, b.y); return r;
}
static __device__ __forceinline__ h2 bch2(unsigned u) {
    union { unsigned u; h2 h; } c; c.u = u; return c.h;
}
static __device__ __forceinline__ unsigned bcu(h2 h) {
    union { h2 h; unsigned u; } c; c.h = h; return c.u;
}

// ---- K1: img_q partials (blocks 0..95: image i = bx>>1, channel-half bx&1)
//          + cap BN partials (blocks 96..255, 12 rows each). 256 blocks = 1/CU.
__global__ __launch_bounds__(256) void k_stats(const float* __restrict__ cap,
                                               const float* __restrict__ img,
                                               float* __restrict__ ps,
                                               float* __restrict__ pss,
                                               unsigned* __restrict__ img_qh,
                                               float* __restrict__ ssqp) {
    __shared__ float sw[4];
    int bx = blockIdx.x, tid = threadIdx.x;
    if (bx < IMGB) {
        int i = bx >> 1, h = bx & 1;
        const float2* img2 = (const float2*)img;
        size_t base = (size_t)i * RR * 512 + h * 256 + tid;  // float2 units
        f2 s = {0.f, 0.f};
#pragma unroll
        for (int r = 0; r < RR; ++r) {
            float2 v = img2[base + (size_t)r * 512];
            s.x += v.x; s.y += v.y;
        }
        const float inv = 1.f / 36.f;
        s.x *= inv; s.y *= inv;
        h2 a; a.x = (_Float16)s.x; a.y = (_Float16)s.y;
        img_qh[(size_t)i * 512 + h * 256 + tid] = bcu(a);
        float ssq = s.x * s.x + s.y * s.y;
#pragma unroll
        for (int off = 32; off; off >>= 1) ssq += __shfl_xor(ssq, off, 64);
        if ((tid & 63) == 0) sw[tid >> 6] = ssq;
        __syncthreads();
        if (tid == 0) ssqp[bx] = sw[0] + sw[1] + sw[2] + sw[3];
    } else {
        int bx2 = bx - IMGB;                 // 0..159
        const float4* cap4 = (const float4*)cap;
        float4 s = {0,0,0,0}, ss = {0,0,0,0};
        int r0 = bx2 * 12;
#pragma unroll
        for (int r = 0; r < 12; ++r) {
            float4 v = cap4[(size_t)(r0 + r) * D4 + tid];
            s.x += v.x; s.y += v.y; s.z += v.z; s.w += v.w;
            ss.x += v.x*v.x; ss.y += v.y*v.y; ss.z += v.z*v.z; ss.w += v.w*v.w;
        }
        ((float4*)ps)[(size_t)bx2 * D4 + tid]  = s;
        ((float4*)pss)[(size_t)bx2 * D4 + tid] = ss;
    }
}

// ---- K2: FiLM GEMMs (blocks 0..511: wave = 1 row x 48 images, f16 LDS +
//          v_dot2_f32_f16; img_q pre-converted) + BN finalize (512..519).
__global__ __launch_bounds__(256) void k_film(const unsigned* __restrict__ img_qh,
                                              const float* __restrict__ Wg,
                                              const float* __restrict__ bg,
                                              const float* __restrict__ Wb,
                                              const float* __restrict__ bb,
                                              const float* __restrict__ ps,
                                              const float* __restrict__ pss,
                                              float* __restrict__ g1,
                                              float* __restrict__ be,
                                              float* __restrict__ mean,
                                              float* __restrict__ scale) {
    __shared__ float smem[12544];            // 50176 B: f16 lq (48KB) / trbuf 4x3136
    int tid = threadIdx.x;

    if (blockIdx.x >= 512) {                 // ---- BN finalize: 8 blocks
        int bx2 = blockIdx.x - 512;          // 0..7
        int c32 = tid & 31;
        int col = bx2 * 32 + c32;            // float4 column 0..255
        int rs  = tid >> 5;                  // 0..7 row-subsets
        const float4* ps4  = (const float4*)ps;
        const float4* pss4 = (const float4*)pss;
        float4 s = {0,0,0,0}, q = {0,0,0,0};
#pragma unroll
        for (int gi = 0; gi < PRG / 8; ++gi) {
            int rg = rs * (PRG / 8) + gi;
            float4 a  = ps4[(size_t)rg * D4 + col];
            float4 b2 = pss4[(size_t)rg * D4 + col];
            s.x += a.x;  s.y += a.y;  s.z += a.z;  s.w += a.w;
            q.x += b2.x; q.y += b2.y; q.z += b2.z; q.w += b2.w;
        }
        float4* red = (float4*)smem;
        red[rs * 32 + c32]       = s;
        red[256 + rs * 32 + c32] = q;
        __syncthreads();
        if (rs == 0) {
            float4 S = {0,0,0,0}, Q = {0,0,0,0};
#pragma unroll
            for (int r2 = 0; r2 < 8; ++r2) {
                float4 a  = red[r2 * 32 + c32];
                float4 b2 = red[256 + r2 * 32 + c32];
                S.x += a.x;  S.y += a.y;  S.z += a.z;  S.w += a.w;
                Q.x += b2.x; Q.y += b2.y; Q.z += b2.z; Q.w += b2.w;
            }
            const float inv = 1.f / 1920.f;
            float4 M = {S.x*inv, S.y*inv, S.z*inv, S.w*inv};
            float4 SC;
            SC.x = rsqrtf(Q.x*inv - M.x*M.x + EPSF);
            SC.y = rsqrtf(Q.y*inv - M.y*M.y + EPSF);
            SC.z = rsqrtf(Q.z*inv - M.z*M.z + EPSF);
            SC.w = rsqrtf(Q.w*inv - M.w*M.w + EPSF);
            ((float4*)mean)[col]  = M;
            ((float4*)scale)[col] = SC;
        }
        return;
    }

    // ---- FiLM GEMM: wave = one virtual row (0..2047), all 48 images
    int wave = tid >> 6, lane = tid & 63;
    int row = blockIdx.x * 4 + wave;         // 0..2047
    int isbeta = row >> 10;
    int d = row & 1023;
    const float4* W4 = (const float4*)(isbeta ? Wb : Wg);

    // prefetch W: lane owns k = half*512 + lane*8 .. +7 (2 float4 per half)
    h2 wh[2][4];
#pragma unroll
    for (int half = 0; half < 2; ++half) {
#pragma unroll
        for (int j = 0; j < 2; ++j) {
            float4 w = W4[(size_t)d * D4 + half * 128 + lane * 2 + j];
            h2 a; a.x = (_Float16)w.x; a.y = (_Float16)w.y;
            h2 b; b.x = (_Float16)w.z; b.y = (_Float16)w.w;
            wh[half][j * 2 + 0] = a;
            wh[half][j * 2 + 1] = b;
        }
    }

    float acc[BI];
#pragma unroll
    for (int i = 0; i < BI; ++i) acc[i] = 0.f;

    const uint4* qh4 = (const uint4*)img_qh; // [i][128] uint4 = 8 f16 each
    uint4* lq_st = (uint4*)smem;             // staging view
    const uint4* lqh4 = (const uint4*)smem;  // read view
#pragma unroll
    for (int half = 0; half < 2; ++half) {
        __syncthreads();
        // stage 48 img x 512 k (f16, raw copy): 3072 uint4, 12 per thread
        for (int idx = tid; idx < BI * 64; idx += 256) {
            int img = idx >> 6, j = idx & 63;
            lq_st[idx] = qh4[(size_t)img * 128 + half * 64 + j];
        }
        __syncthreads();
#pragma unroll
        for (int i = 0; i < BI; ++i) {
            uint4 r = lqh4[i * 64 + lane];   // 8 k of image i
            acc[i] = __builtin_amdgcn_fdot2(wh[half][0], bch2(r.x), acc[i], false);
            acc[i] = __builtin_amdgcn_fdot2(wh[half][1], bch2(r.y), acc[i], false);
            acc[i] = __builtin_amdgcn_fdot2(wh[half][2], bch2(r.z), acc[i], false);
            acc[i] = __builtin_amdgcn_fdot2(wh[half][3], bch2(r.w), acc[i], false);
        }
    }
    // transpose-reduce: wave-private LDS region, stride 49 (conflict-free)
    __syncthreads();                         // all waves done reading lq
    float* tr = smem + wave * 3136;          // 64*49 floats
#pragma unroll
    for (int i = 0; i < BI; ++i) tr[lane * 49 + i] = acc[i];
    float s0 = 0.f, s1 = 0.f, s2 = 0.f, s3 = 0.f;
#pragma unroll
    for (int l = 0; l < 64; l += 4) {
        s0 += tr[(l + 0) * 49 + lane];
        s1 += tr[(l + 1) * 49 + lane];
        s2 += tr[(l + 2) * 49 + lane];
        s3 += tr[(l + 3) * 49 + lane];
    }
    float sum = (s0 + s1) + (s2 + s3);
    if (lane < BI) {
        float badd = isbeta ? bb[d] : (bg[d] + 1.f);   // store 1+gamma
        float* outp = isbeta ? be : g1;
        outp[(size_t)lane * D + d] = sum + badd;
    }
}

// ---- K3: fused BN-normalize + Fovea + l2norm + cosine.
// 768 blocks = (b, 3 images); packed-f32 math; XCD-bijective swizzle.
// img_n computed on the fly from f16 img_qh + ssq partial pair (replay-safe,
// no atomics: f32 add of two fixed partials is order-independent).
__global__ __launch_bounds__(256) void k_fovea(const float* __restrict__ cap,
                                               const float* __restrict__ mean,
                                               const float* __restrict__ scale,
                                               const float* __restrict__ g1,
                                               const float* __restrict__ be,
                                               const unsigned* __restrict__ img_qh,
                                               const float* __restrict__ ssqp,
                                               float* __restrict__ out) {
    int j = blockIdx.x;                      // 768 items
    int wg = (j & 7) * 96 + (j >> 3);        // bijective XCD swizzle (768 % 8 == 0)
    int b = wg >> 4, ig = wg & 15;
    int i0 = ig * 3;
    int tid = threadIdx.x;

    const float4* cap4 = (const float4*)cap;
    float4 m4  = ((const float4*)mean)[tid];
    float4 sc4 = ((const float4*)scale)[tid];
    f2 mm0 = {m4.x, m4.y},  mm1 = {m4.z, m4.w};
    f2 sc0 = {sc4.x, sc4.y}, sc1 = {sc4.z, sc4.w};

    // G2 = g*sc*L2E ; B2 = (bt - g*sc*m)*L2E
    f2 G2[3][2], B2[3][2];
#pragma unroll
    for (int u = 0; u < 3; ++u) {
        float4 t0 = ((const float4*)g1)[(size_t)(i0 + u) * D4 + tid];
        float4 u0 = ((const float4*)be)[(size_t)(i0 + u) * D4 + tid];
        f2 gg0 = {t0.x, t0.y}, gg1 = {t0.z, t0.w};
        f2 bt0 = {u0.x, u0.y}, bt1 = {u0.z, u0.w};
        f2 tt0 = gg0 * sc0, tt1 = gg1 * sc1;
        G2[u][0] = tt0 * L2E;
        G2[u][1] = tt1 * L2E;
        B2[u][0] = (bt0 - tt0 * mm0) * L2E;
        B2[u][1] = (bt1 - tt1 * mm1) * L2E;
    }
    f2 se[3][2], vm[3][2];
#pragma unroll
    for (int u = 0; u < 3; ++u)
#pragma unroll
        for (int c = 0; c < 2; ++c) {
            se[u][c] = (f2){0.f, 0.f};
            vm[u][c] = (f2){-INFINITY, -INFINITY};
        }

#pragma unroll 4
    for (int t = 0; t < TT; ++t) {
        float4 c4 = cap4[((size_t)b * TT + t) * D4 + tid];
        f2 cc0 = {c4.x, c4.y}, cc1 = {c4.z, c4.w};
#pragma unroll
        for (int u = 0; u < 3; ++u) {
            f2 y0 = cc0 * G2[u][0] + B2[u][0];
            f2 y1 = cc1 * G2[u][1] + B2[u][1];
            f2 e0, e1;
            e0.x = __builtin_amdgcn_exp2f(y0.x);
            e0.y = __builtin_amdgcn_exp2f(y0.y);
            e1.x = __builtin_amdgcn_exp2f(y1.x);
            e1.y = __builtin_amdgcn_exp2f(y1.y);
            se[u][0] += e0;
            se[u][1] += e1;
            vm[u][0] = f2max(vm[u][0], y0 * e0);
            vm[u][1] = f2max(vm[u][1], y1 * e1);
        }
    }
    float dd[3], sq[3];
#pragma unroll
    for (int u = 0; u < 3; ++u) {
        uint2 qw = ((const uint2*)img_qh)[(size_t)(i0 + u) * D4 + tid];
        h2 qa = bch2(qw.x), qb = bch2(qw.y);
        float rv = rsqrtf(ssqp[2 * (i0 + u)] + ssqp[2 * (i0 + u) + 1]);
        float n0 = (float)qa.x * rv, n1 = (float)qa.y * rv;
        float n2 = (float)qb.x * rv, n3 = (float)qb.y * rv;
        f2 r0, r1;
        r0.x = __builtin_amdgcn_rcpf(se[u][0].x);
        r0.y = __builtin_amdgcn_rcpf(se[u][0].y);
        r1.x = __builtin_amdgcn_rcpf(se[u][1].x);
        r1.y = __builtin_amdgcn_rcpf(se[u][1].y);
        f2 v0 = vm[u][0] * r0, v1 = vm[u][1] * r1;
        sq[u] = v0.x*v0.x + v0.y*v0.y + v1.x*v1.x + v1.y*v1.y;
        dd[u] = v0.x*n0 + v0.y*n1 + v1.x*n2 + v1.y*n3;
    }
#pragma unroll
    for (int off = 32; off; off >>= 1) {
#pragma unroll
        for (int u = 0; u < 3; ++u) {
            dd[u] += __shfl_xor(dd[u], off, 64);
            sq[u] += __shfl_xor(sq[u], off, 64);
        }
    }
    __shared__ float rd[3][4], rq[3][4];     // [u][wave]
    int wave = tid >> 6, lane = tid & 63;
    if (lane == 0) {
#pragma unroll
        for (int u = 0; u < 3; ++u) { rd[u][wave] = dd[u]; rq[u][wave] = sq[u]; }
    }
    __syncthreads();
    if (tid < 3) {
        float td = rd[tid][0] + rd[tid][1] + rd[tid][2] + rd[tid][3];
        float ts = rq[tid][0] + rq[tid][1] + rq[tid][2] + rq[tid][3];
        out[(size_t)(i0 + tid) * BC + b] = td / sqrtf(ts);
    }
}

extern "C" void kernel_launch(void* const* d_in, const int* in_sizes, int n_in,
                              void* d_out, int out_size, void* d_ws, size_t ws_size,
                              hipStream_t stream) {
    const float* img = (const float*)d_in[0];
    const float* cap = (const float*)d_in[1];
    // d_in[2] = lens (unused)
    const float* Wg  = (const float*)d_in[3];
    const float* bg  = (const float*)d_in[4];
    const float* Wb  = (const float*)d_in[5];
    const float* bb  = (const float*)d_in[6];
    float* out = (float*)d_out;

    float* ws     = (float*)d_ws;
    float* ps     = ws;                        // 160*1024
    float* pss    = ps  + PRG * D;             // 160*1024
    unsigned* img_qh = (unsigned*)(pss + PRG * D);  // 48*512 u32 (f16 pairs)
    float* ssqp   = (float*)(img_qh + BI * 512);    // 96
    float* g1     = ssqp + 96;                 // 48*1024
    float* be     = g1   + BI * D;             // 48*1024
    float* mean   = be   + BI * D;             // 1024
    float* scale  = mean + D;                  // 1024

    hipLaunchKernelGGL(k_stats, dim3(IMGB + PRG), dim3(256), 0, stream,
                       cap, img, ps, pss, img_qh, ssqp);
    hipLaunchKernelGGL(k_film,  dim3(520),       dim3(256), 0, stream,
                       img_qh, Wg, bg, Wb, bb, ps, pss, g1, be, mean, scale);
    hipLaunchKernelGGL(k_fovea, dim3(768),       dim3(256), 0, stream,
                       cap, mean, scale, g1, be, img_qh, ssqp, out);
}